// Round 1
// baseline (1479.863 us; speedup 1.0000x reference)
//
#include <hip/hip_runtime.h>
#include <stdint.h>

#define NND   50000      // real nodes
#define NPAD  50048      // padded to 391*128 for GEMM M-tiles
#define NBLK  196        // ceil(50001/256) scan blocks
#define EPS_BN 1e-5f

typedef __attribute__((ext_vector_type(8))) short    s16x8;
typedef __attribute__((ext_vector_type(8))) __bf16   bf16x8;
typedef __attribute__((ext_vector_type(4))) float    f32x4;

#define AS1 __attribute__((address_space(1)))
#define AS3 __attribute__((address_space(3)))

__device__ __forceinline__ float bflo(uint32_t v){ return __uint_as_float(v << 16); }
__device__ __forceinline__ float bfhi(uint32_t v){ return __uint_as_float(v & 0xffff0000u); }
__device__ __forceinline__ uint32_t f2bf1(float f){
  uint32_t u = __float_as_uint(f);
  return (u + 0x7fffu + ((u >> 16) & 1u)) >> 16;   // RNE
}
__device__ __forceinline__ uint32_t f2bf2(float lo, float hi){
  return f2bf1(lo) | (f2bf1(hi) << 16);
}

// ---------------- CSR build ----------------
__global__ void k_count(const int* __restrict__ row0, const int* __restrict__ col0, int E,
                        int* __restrict__ cnt_col, int* __restrict__ cnt_row){
  int e = blockIdx.x * 256 + threadIdx.x;
  if (e < E){
    atomicAdd(&cnt_col[col0[e]], 1);
    atomicAdd(&cnt_row[row0[e]], 1);
  }
}

__global__ void k_scan1(const int* __restrict__ ca, const int* __restrict__ cb,
                        int* __restrict__ bsum){
  const int* c = blockIdx.y ? cb : ca;
  int i = blockIdx.x * 256 + threadIdx.x;
  int v = (i < NND) ? c[i] : 0;
  __shared__ int s[256];
  s[threadIdx.x] = v; __syncthreads();
  for (int o = 128; o > 0; o >>= 1){
    if (threadIdx.x < o) s[threadIdx.x] += s[threadIdx.x + o];
    __syncthreads();
  }
  if (threadIdx.x == 0) bsum[blockIdx.y * NBLK + blockIdx.x] = s[0];
}

__global__ void k_scan2(const int* __restrict__ bsum, int* __restrict__ boff){
  int a = blockIdx.y, t = threadIdx.x;
  int v = (t < NBLK) ? bsum[a * NBLK + t] : 0;
  __shared__ int s[256];
  s[t] = v; __syncthreads();
  for (int o = 1; o < 256; o <<= 1){
    int x = (t >= o) ? s[t - o] : 0; __syncthreads();
    s[t] += x; __syncthreads();
  }
  if (t < NBLK) boff[a * NBLK + t] = s[t] - v;   // exclusive
}

__global__ void k_scan3(const int* __restrict__ ca, const int* __restrict__ cb,
                        const int* __restrict__ boff,
                        int* __restrict__ offa, int* __restrict__ offb,
                        int* __restrict__ cura, int* __restrict__ curb){
  int a = blockIdx.y, t = threadIdx.x;
  const int* c = a ? cb : ca;
  int* off = a ? offb : offa;
  int* cur = a ? curb : cura;
  int i = blockIdx.x * 256 + t;
  int v = (i < NND) ? c[i] : 0;
  __shared__ int s[256];
  s[t] = v; __syncthreads();
  for (int o = 1; o < 256; o <<= 1){
    int x = (t >= o) ? s[t - o] : 0; __syncthreads();
    s[t] += x; __syncthreads();
  }
  int excl = s[t] - v + boff[a * NBLK + blockIdx.x];
  if (i <= NND){ off[i] = excl; if (i < NND) cur[i] = excl; }
}

__global__ void k_dis(const int* __restrict__ cnt_col, float* __restrict__ dis){
  int i = blockIdx.x * 256 + threadIdx.x;
  if (i < NND) dis[i] = rsqrtf((float)(cnt_col[i] + 1));   // deg incl self-loop >= 1
}

__global__ void k_fill(const int* __restrict__ row0, const int* __restrict__ col0, int E,
                       int* __restrict__ cur_col, int* __restrict__ cur_row,
                       int* __restrict__ adjA, int* __restrict__ adjB){
  int e = blockIdx.x * 256 + threadIdx.x;
  if (e < E){
    int r = row0[e], c = col0[e];
    adjA[atomicAdd(&cur_col[c], 1)] = r;   // grouped by dst(col), stores src(row)
    adjB[atomicAdd(&cur_row[r], 1)] = c;   // grouped by row0, stores col0
  }
}

// ---------------- casts ----------------
__global__ void k_cast(const float* __restrict__ x, uint32_t* __restrict__ o, size_t npairs){
  size_t i = (size_t)blockIdx.x * blockDim.x + threadIdx.x;
  if (i < npairs){
    float2 v = ((const float2*)x)[i];
    o[i] = f2bf2(v.x, v.y);
  }
}

// W [K][N] f32 -> Wt [N][K] bf16
__global__ void k_castT(const float* __restrict__ W, uint16_t* __restrict__ Wt, int K, int N){
  __shared__ float tile[32][33];
  int k0 = blockIdx.x * 32, n0 = blockIdx.y * 32;
  int tx = threadIdx.x & 31, ty = threadIdx.x >> 5;
  for (int j = ty; j < 32; j += 8) tile[j][tx] = W[(size_t)(k0 + j) * N + n0 + tx];
  __syncthreads();
  for (int j = ty; j < 32; j += 8)
    Wt[(size_t)(n0 + j) * K + k0 + tx] = (uint16_t)f2bf1(tile[tx][j]);
}

// ---------------- bf16 MFMA GEMM: C[row][col] = bf16(dis[row] * sum_k A[row][k]*Bt[col][k]) ----------------
// A [M=NPAD][K] bf16 row-major (pad rows zeroed), Bt [N][K] bf16, 128x128 tile, BK=64, 4 waves.
__global__ __launch_bounds__(256) void k_gemm(
    const uint16_t* __restrict__ A, const uint16_t* __restrict__ Bt,
    uint16_t* __restrict__ C, const float* __restrict__ dis,
    int K, int N, int Mreal){
  __shared__ uint16_t lA[128 * 64];
  __shared__ uint16_t lB[128 * 64];
  const int tid = threadIdx.x, w = tid >> 6, l = tid & 63;
  const int tm = blockIdx.x * 128, tn = blockIdx.y * 128;
  const int wm = (w >> 1) * 64, wn = (w & 1) * 64;
  f32x4 acc[4][4] = {};
  const int srow = w * 32 + (l >> 3);     // staging row within tile (8 rows/instr)
  const int kcol = (l & 7) * 8;           // staging k-offset (16B per lane)
  const uint16_t* ga = A  + (size_t)(tm + srow) * K + kcol;
  const uint16_t* gb = Bt + (size_t)(tn + srow) * K + kcol;
  char* la0 = (char*)lA + (w * 32) * 128;
  char* lb0 = (char*)lB + (w * 32) * 128;

  for (int kt = 0; kt < K; kt += 64){
    __syncthreads();
#pragma unroll
    for (int t = 0; t < 4; t++){
      __builtin_amdgcn_global_load_lds((AS1 void*)(ga + (size_t)t * 8 * K + kt),
                                       (AS3 void*)(la0 + t * 8 * 128), 16, 0, 0);
      __builtin_amdgcn_global_load_lds((AS1 void*)(gb + (size_t)t * 8 * K + kt),
                                       (AS3 void*)(lb0 + t * 8 * 128), 16, 0, 0);
    }
    __syncthreads();
#pragma unroll
    for (int kk = 0; kk < 2; kk++){
      s16x8 af[4], bfr[4];
#pragma unroll
      for (int mf = 0; mf < 4; mf++)
        af[mf] = *(const s16x8*)&lA[(wm + mf * 16 + (l & 15)) * 64 + kk * 32 + (l >> 4) * 8];
#pragma unroll
      for (int nf = 0; nf < 4; nf++)
        bfr[nf] = *(const s16x8*)&lB[(wn + nf * 16 + (l & 15)) * 64 + kk * 32 + (l >> 4) * 8];
#pragma unroll
      for (int mf = 0; mf < 4; mf++)
#pragma unroll
        for (int nf = 0; nf < 4; nf++)
          acc[mf][nf] = __builtin_amdgcn_mfma_f32_16x16x32_bf16(
              __builtin_bit_cast(bf16x8, af[mf]),
              __builtin_bit_cast(bf16x8, bfr[nf]),
              acc[mf][nf], 0, 0, 0);
    }
  }
  // epilogue: D[row=(l>>4)*4+r][col=l&15] per 16x16 frag (verified layout)
#pragma unroll
  for (int mf = 0; mf < 4; mf++){
#pragma unroll
    for (int r = 0; r < 4; r++){
      int row = tm + wm + mf * 16 + (l >> 4) * 4 + r;
      if (row < Mreal){
        float d = dis[row];
#pragma unroll
        for (int nf = 0; nf < 4; nf++){
          int col = tn + wn + nf * 16 + (l & 15);
          C[(size_t)row * N + col] = (uint16_t)f2bf1(acc[mf][nf][r] * d);
        }
      }
    }
  }
}

// ---------------- SpMM (CSR gather-sum) ----------------
// MODE 0: STRC  (no self, no dis, no bias; out bf16)
// MODE 1: GCN   (self + dis + bias; out bf16)
// MODE 2: GCN   (self + dis + bias; out f32)
// X: [*, FH] uint32 (2 bf16/row-elem). rows of X already scaled by dis[src] for GCN.
template<int FH, int MODE>
__global__ void k_spmm(const uint32_t* __restrict__ X,
                       const int* __restrict__ off, const int* __restrict__ adj,
                       const float* __restrict__ dis, const float* __restrict__ bias,
                       void* __restrict__ outp){
  const int n = blockIdx.x;
  const int t = threadIdx.x;
  int s = off[n], e = off[n + 1];
  float ax = 0.f, ay = 0.f;
  if (MODE != 0){
    uint32_t v = X[(size_t)n * FH + t];   // self-loop term
    ax = bflo(v); ay = bfhi(v);
  }
  int j = s;
  for (; j + 4 <= e; j += 4){
    int r0 = adj[j], r1 = adj[j + 1], r2 = adj[j + 2], r3 = adj[j + 3];
    uint32_t v0 = X[(size_t)r0 * FH + t], v1 = X[(size_t)r1 * FH + t];
    uint32_t v2 = X[(size_t)r2 * FH + t], v3 = X[(size_t)r3 * FH + t];
    ax += bflo(v0) + bflo(v1) + bflo(v2) + bflo(v3);
    ay += bfhi(v0) + bfhi(v1) + bfhi(v2) + bfhi(v3);
  }
  for (; j < e; ++j){
    uint32_t v = X[(size_t)adj[j] * FH + t];
    ax += bflo(v); ay += bfhi(v);
  }
  if (MODE != 0){
    float d = dis[n];
    float2 b = ((const float2*)bias)[t];
    ax = fmaf(ax, d, b.x); ay = fmaf(ay, d, b.y);
  }
  if (MODE == 2) ((float2*)outp)[(size_t)n * FH + t] = make_float2(ax, ay);
  else           ((uint32_t*)outp)[(size_t)n * FH + t] = f2bf2(ax, ay);
}

// ---------------- BN ----------------
template<int FH>
__global__ void k_stats(const uint32_t* __restrict__ X, float* __restrict__ sums){
  const int t = threadIdx.x;
  float sx = 0, sy = 0, qx = 0, qy = 0;
  for (int r = blockIdx.x; r < NND; r += gridDim.x){
    uint32_t v = X[(size_t)r * FH + t];
    float x = bflo(v), y = bfhi(v);
    sx += x; sy += y; qx += x * x; qy += y * y;
  }
  atomicAdd(&sums[2 * t    ], sx);
  atomicAdd(&sums[2 * t + 1], sy);
  atomicAdd(&sums[2 * FH + 2 * t    ], qx);
  atomicAdd(&sums[2 * FH + 2 * t + 1], qy);
}

__global__ void k_bnfin(const float* __restrict__ sums, int F, float inv,
                        const float* __restrict__ gamma, const float* __restrict__ beta,
                        float* __restrict__ scsh){
  int f = blockIdx.x * blockDim.x + threadIdx.x;
  if (f >= F) return;
  float mu  = sums[f] * inv;
  float var = fmaxf(sums[F + f] * inv - mu * mu, 0.f);
  float sc  = gamma[f] * rsqrtf(var + EPS_BN);
  scsh[f]     = sc;
  scsh[F + f] = beta[f] - mu * sc;
}

template<int FH, bool RELU>
__global__ void k_bnapply(const uint32_t* __restrict__ X, const float* __restrict__ scsh,
                          uint32_t* __restrict__ out){
  size_t i = (size_t)blockIdx.x * blockDim.x + threadIdx.x;
  if (i >= (size_t)NND * FH) return;
  int t = (int)(i & (FH - 1));
  uint32_t v = X[i];
  float2 sc = ((const float2*)scsh)[t];
  float2 sh = ((const float2*)(scsh + 2 * FH))[t];
  float x = fmaf(sc.x, bflo(v), sh.x);
  float y = fmaf(sc.y, bfhi(v), sh.y);
  if (RELU){ x = fmaxf(x, 0.f); y = fmaxf(y, 0.f); }
  out[i] = f2bf2(x, y);
}

// ---------------- final combine: out = p0*x2 + p1*0.5*(Wc1 + bn1(temp2)) ----------------
__global__ void k_final(const float2* __restrict__ x2, const uint32_t* __restrict__ wc1,
                        const uint32_t* __restrict__ t2, const float* __restrict__ scsh,
                        const float* __restrict__ policy, float2* __restrict__ outp){
  size_t i = (size_t)blockIdx.x * blockDim.x + threadIdx.x;
  if (i >= (size_t)NND * 128) return;
  int t = (int)(i & 127);
  float2 sc = ((const float2*)scsh)[t];
  float2 sh = ((const float2*)(scsh + 256))[t];
  float a = policy[0], b = policy[1];
  float m = fmaxf(a, b);
  float e0 = expf(a - m), e1 = expf(b - m);
  float p0 = e0 / (e0 + e1), p1 = 1.f - p0;
  uint32_t w = wc1[i], v = t2[i];
  float xax = 0.5f * (bflo(w) + fmaf(sc.x, bflo(v), sh.x));
  float xay = 0.5f * (bfhi(w) + fmaf(sc.y, bfhi(v), sh.y));
  float2 xv = x2[i];
  outp[i] = make_float2(fmaf(p0, xv.x, p1 * xax), fmaf(p0, xv.y, p1 * xay));
}

// ---------------- launcher ----------------
extern "C" void kernel_launch(void* const* d_in, const int* in_sizes, int n_in,
                              void* d_out, int out_size, void* d_ws, size_t ws_size,
                              hipStream_t stream) {
  const float* node_feat = (const float*)d_in[0];
  const float* W1    = (const float*)d_in[1];
  const float* b1    = (const float*)d_in[2];
  const float* W2    = (const float*)d_in[3];
  const float* b2    = (const float*)d_in[4];
  const float* g1    = (const float*)d_in[5];
  const float* be1   = (const float*)d_in[6];
  const float* strcW = (const float*)d_in[7];
  const float* sg    = (const float*)d_in[8];
  const float* sb    = (const float*)d_in[9];
  const float* pol   = (const float*)d_in[10];
  const int*   eidx  = (const int*)d_in[11];
  const int E = in_sizes[11] / 2;
  const int* row0 = eidx;
  const int* col0 = eidx + E;

  char* w = (char*)d_ws;
  auto alloc = [&](size_t bytes) -> char* {
    char* p = w; w += (bytes + 255) & ~(size_t)255; return p;
  };
  // meta (zeroed once per call)
  char* meta0   = w;
  int*  cnt_col = (int*)alloc(50176 * 4);
  int*  cnt_row = (int*)alloc(50176 * 4);
  int*  off_col = (int*)alloc(50432 * 4);
  int*  off_row = (int*)alloc(50432 * 4);
  int*  cur_col = (int*)alloc(50176 * 4);
  int*  cur_row = (int*)alloc(50176 * 4);
  int*  bsum    = (int*)alloc(512 * 4);
  int*  boff    = (int*)alloc(512 * 4);
  float* dis    = (float*)alloc(50048 * 4);
  float* sums1  = (float*)alloc(1024 * 4);
  float* sums2  = (float*)alloc(512 * 4);
  float* sums3  = (float*)alloc(512 * 4);
  float* scsh1  = (float*)alloc(1024 * 4);
  float* scsh2  = (float*)alloc(512 * 4);
  float* scsh3  = (float*)alloc(512 * 4);
  char* meta1   = w;
  int*  adjA = (int*)alloc((size_t)E * 4);
  int*  adjB = (int*)alloc((size_t)E * 4);
  uint16_t* W1t = (uint16_t*)alloc(512 * 512 * 2);
  uint16_t* W2t = (uint16_t*)alloc(256 * 512 * 2);
  // big buffers with lifetime reuse
  char* BUF_B = alloc((size_t)NPAD * 512 * 2);  // Xb -> agg1b -> H2b -> temp/temp2
  char* BUF_C = alloc((size_t)NPAD * 512 * 2);  // Hb -> X2b -> x2(f32)
  char* BUF_D = alloc((size_t)NND * 256 * 2);   // strcW bf16 -> Wc1 bf16
  (void)n_in; (void)out_size; (void)ws_size;

  hipMemsetAsync(meta0, 0, (size_t)(meta1 - meta0), stream);
  hipMemsetAsync(BUF_B + (size_t)NND * 1024, 0, (size_t)(NPAD - NND) * 1024, stream); // Xb pad rows

  const int EB = (E + 255) / 256;
  // CSR build
  k_count<<<EB, 256, 0, stream>>>(row0, col0, E, cnt_col, cnt_row);
  k_scan1<<<dim3(NBLK, 2), 256, 0, stream>>>(cnt_col, cnt_row, bsum);
  k_scan2<<<dim3(1, 2), 256, 0, stream>>>(bsum, boff);
  k_scan3<<<dim3(NBLK, 2), 256, 0, stream>>>(cnt_col, cnt_row, boff,
                                             off_col, off_row, cur_col, cur_row);
  k_dis<<<(NND + 255) / 256, 256, 0, stream>>>(cnt_col, dis);
  k_fill<<<EB, 256, 0, stream>>>(row0, col0, E, cur_col, cur_row, adjA, adjB);

  // casts
  k_cast<<<(NND * 256 + 255) / 256, 256, 0, stream>>>(node_feat, (uint32_t*)BUF_B, (size_t)NND * 256);
  k_cast<<<(NND * 128 + 255) / 256, 256, 0, stream>>>(strcW, (uint32_t*)BUF_D, (size_t)NND * 128);
  k_castT<<<dim3(16, 16), 256, 0, stream>>>(W1, W1t, 512, 512);
  k_castT<<<dim3(16, 8), 256, 0, stream>>>(W2, W2t, 512, 256);

  // GCN conv1: H = X@W1 (epilogue: *dis[row] -> bf16), then aggregate
  k_gemm<<<dim3(NPAD / 128, 4), 256, 0, stream>>>((const uint16_t*)BUF_B, W1t,
                                                  (uint16_t*)BUF_C, dis, 512, 512, NND);
  k_spmm<256, 1><<<NND, 256, 0, stream>>>((const uint32_t*)BUF_C, off_col, adjA,
                                          dis, b1, BUF_B);                 // agg1 bf16 -> B
  // BN1 + relu -> X2 bf16 (C), pad rows zeroed first (C's Hb is dead now)
  k_stats<256><<<512, 256, 0, stream>>>((const uint32_t*)BUF_B, sums1);
  k_bnfin<<<2, 256, 0, stream>>>(sums1, 512, 1.f / NND, g1, be1, scsh1);
  hipMemsetAsync(BUF_C + (size_t)NND * 1024, 0, (size_t)(NPAD - NND) * 1024, stream);
  k_bnapply<256, true><<<(NND * 256 + 255) / 256, 256, 0, stream>>>(
      (const uint32_t*)BUF_B, scsh1, (uint32_t*)BUF_C);
  // GCN conv2
  k_gemm<<<dim3(NPAD / 128, 2), 256, 0, stream>>>((const uint16_t*)BUF_C, W2t,
                                                  (uint16_t*)BUF_B, dis, 512, 256, NND);
  k_spmm<128, 2><<<NND, 128, 0, stream>>>((const uint32_t*)BUF_B, off_col, adjA,
                                          dis, b2, BUF_C);                 // x2 f32 -> C

  // STRC branch: temp = A@Wc (group by row0, gather col0), BN per power step
  k_spmm<128, 0><<<NND, 128, 0, stream>>>((const uint32_t*)BUF_D, off_row, adjB,
                                          nullptr, nullptr, BUF_B);        // temp bf16 -> B
  k_stats<128><<<512, 128, 0, stream>>>((const uint32_t*)BUF_B, sums2);
  k_bnfin<<<1, 256, 0, stream>>>(sums2, 256, 1.f / NND, sg, sb, scsh2);
  k_bnapply<128, false><<<(NND * 128 + 255) / 256, 256, 0, stream>>>(
      (const uint32_t*)BUF_B, scsh2, (uint32_t*)BUF_D);                    // Wc1 bf16 -> D
  k_spmm<128, 0><<<NND, 128, 0, stream>>>((const uint32_t*)BUF_D, off_row, adjB,
                                          nullptr, nullptr, BUF_B);        // temp2 bf16 -> B
  k_stats<128><<<512, 128, 0, stream>>>((const uint32_t*)BUF_B, sums3);
  k_bnfin<<<1, 256, 0, stream>>>(sums3, 256, 1.f / NND, sg + 256, sb + 256, scsh3);

  // out = p0*x2 + p1*0.5*(Wc1 + bn(temp2))
  k_final<<<(NND * 128 + 255) / 256, 256, 0, stream>>>(
      (const float2*)BUF_C, (const uint32_t*)BUF_D, (const uint32_t*)BUF_B,
      scsh3, pol, (float2*)d_out);
}

// Round 2
// 1373.572 us; speedup vs baseline: 1.0774x; 1.0774x over previous
//
#include <hip/hip_runtime.h>
#include <stdint.h>

#define NND   50000      // real nodes
#define NPAD  50048      // padded to 391*128 for GEMM M-tiles
#define NBLK  196        // ceil(50001/256) scan blocks
#define NRANGE 7         // fill rounds: dst>>13, max 49999>>13 = 6
#define EPS_BN 1e-5f

typedef __attribute__((ext_vector_type(8))) short    s16x8;
typedef __attribute__((ext_vector_type(8))) __bf16   bf16x8;
typedef __attribute__((ext_vector_type(4))) float    f32x4;

#define AS1 __attribute__((address_space(1)))
#define AS3 __attribute__((address_space(3)))

__device__ __forceinline__ float bflo(uint32_t v){ return __uint_as_float(v << 16); }
__device__ __forceinline__ float bfhi(uint32_t v){ return __uint_as_float(v & 0xffff0000u); }
__device__ __forceinline__ uint32_t f2bf1(float f){
  uint32_t u = __float_as_uint(f);
  return (u + 0x7fffu + ((u >> 16) & 1u)) >> 16;   // RNE
}
__device__ __forceinline__ uint32_t f2bf2(float lo, float hi){
  return f2bf1(lo) | (f2bf1(hi) << 16);
}

// ---------------- CSR build ----------------
__global__ void k_count(const int* __restrict__ row0, const int* __restrict__ col0, int E,
                        int* __restrict__ cnt_col, int* __restrict__ cnt_row){
  int e = blockIdx.x * 256 + threadIdx.x;
  if (e < E){
    atomicAdd(&cnt_col[col0[e]], 1);
    atomicAdd(&cnt_row[row0[e]], 1);
  }
}

__global__ void k_scan1(const int* __restrict__ ca, const int* __restrict__ cb,
                        int* __restrict__ bsum){
  const int* c = blockIdx.y ? cb : ca;
  int i = blockIdx.x * 256 + threadIdx.x;
  int v = (i < NND) ? c[i] : 0;
  __shared__ int s[256];
  s[threadIdx.x] = v; __syncthreads();
  for (int o = 128; o > 0; o >>= 1){
    if (threadIdx.x < o) s[threadIdx.x] += s[threadIdx.x + o];
    __syncthreads();
  }
  if (threadIdx.x == 0) bsum[blockIdx.y * NBLK + blockIdx.x] = s[0];
}

__global__ void k_scan2(const int* __restrict__ bsum, int* __restrict__ boff){
  int a = blockIdx.y, t = threadIdx.x;
  int v = (t < NBLK) ? bsum[a * NBLK + t] : 0;
  __shared__ int s[256];
  s[t] = v; __syncthreads();
  for (int o = 1; o < 256; o <<= 1){
    int x = (t >= o) ? s[t - o] : 0; __syncthreads();
    s[t] += x; __syncthreads();
  }
  if (t < NBLK) boff[a * NBLK + t] = s[t] - v;   // exclusive
}

__global__ void k_scan3(const int* __restrict__ ca, const int* __restrict__ cb,
                        const int* __restrict__ boff,
                        int* __restrict__ offa, int* __restrict__ offb,
                        int* __restrict__ cura, int* __restrict__ curb){
  int a = blockIdx.y, t = threadIdx.x;
  const int* c = a ? cb : ca;
  int* off = a ? offb : offa;
  int* cur = a ? curb : cura;
  int i = blockIdx.x * 256 + t;
  int v = (i < NND) ? c[i] : 0;
  __shared__ int s[256];
  s[t] = v; __syncthreads();
  for (int o = 1; o < 256; o <<= 1){
    int x = (t >= o) ? s[t - o] : 0; __syncthreads();
    s[t] += x; __syncthreads();
  }
  int excl = s[t] - v + boff[a * NBLK + blockIdx.x];
  if (i <= NND){ off[i] = excl; if (i < NND) cur[i] = excl; }
}

__global__ void k_dis(const int* __restrict__ cnt_col, float* __restrict__ dis){
  int i = blockIdx.x * 256 + threadIdx.x;
  if (i < NND) dis[i] = rsqrtf((float)(cnt_col[i] + 1));   // deg incl self-loop >= 1
}

// Range-partitioned fill: consecutive blocks handle the same dst range so the
// concurrently-active scatter region (~0.9 MB) stays resident in L2 -> lines
// fill fully before eviction (kills the 15x partial-line write amplification).
__global__ void k_fill(const int* __restrict__ row0, const int* __restrict__ col0,
                       int E, int EB,
                       int* __restrict__ cur_col, int* __restrict__ cur_row,
                       int* __restrict__ adjA, int* __restrict__ adjB){
  int round = blockIdx.x / EB;
  int e = (blockIdx.x - round * EB) * 256 + threadIdx.x;
  if (e >= E) return;
  int r = row0[e], c = col0[e];
  if ((c >> 13) == round) adjA[atomicAdd(&cur_col[c], 1)] = r;  // by dst(col), stores src
  if ((r >> 13) == round) adjB[atomicAdd(&cur_row[r], 1)] = c;  // by row0, stores col0
}

// ---------------- casts ----------------
__global__ void k_cast(const float* __restrict__ x, uint2* __restrict__ o, size_t nq){
  size_t i = (size_t)blockIdx.x * blockDim.x + threadIdx.x;
  if (i < nq){
    float4 v = ((const float4*)x)[i];
    o[i] = make_uint2(f2bf2(v.x, v.y), f2bf2(v.z, v.w));
  }
}

// W [K][N] f32 -> Wt [N][K] bf16
__global__ void k_castT(const float* __restrict__ W, uint16_t* __restrict__ Wt, int K, int N){
  __shared__ float tile[32][33];
  int k0 = blockIdx.x * 32, n0 = blockIdx.y * 32;
  int tx = threadIdx.x & 31, ty = threadIdx.x >> 5;
  for (int j = ty; j < 32; j += 8) tile[j][tx] = W[(size_t)(k0 + j) * N + n0 + tx];
  __syncthreads();
  for (int j = ty; j < 32; j += 8)
    Wt[(size_t)(n0 + j) * K + k0 + tx] = (uint16_t)f2bf1(tile[tx][j]);
}

// ---------------- bf16 MFMA GEMM: C[row][col] = bf16(dis[row] * sum_k A[row][k]*Bt[col][k]) ----------------
__global__ __launch_bounds__(256) void k_gemm(
    const uint16_t* __restrict__ A, const uint16_t* __restrict__ Bt,
    uint16_t* __restrict__ C, const float* __restrict__ dis,
    int K, int N, int Mreal){
  __shared__ uint16_t lA[128 * 64];
  __shared__ uint16_t lB[128 * 64];
  const int tid = threadIdx.x, w = tid >> 6, l = tid & 63;
  const int tm = blockIdx.x * 128, tn = blockIdx.y * 128;
  const int wm = (w >> 1) * 64, wn = (w & 1) * 64;
  f32x4 acc[4][4] = {};
  const int srow = w * 32 + (l >> 3);
  const int kcol = (l & 7) * 8;
  const uint16_t* ga = A  + (size_t)(tm + srow) * K + kcol;
  const uint16_t* gb = Bt + (size_t)(tn + srow) * K + kcol;
  char* la0 = (char*)lA + (w * 32) * 128;
  char* lb0 = (char*)lB + (w * 32) * 128;

  for (int kt = 0; kt < K; kt += 64){
    __syncthreads();
#pragma unroll
    for (int t = 0; t < 4; t++){
      __builtin_amdgcn_global_load_lds((AS1 void*)(ga + (size_t)t * 8 * K + kt),
                                       (AS3 void*)(la0 + t * 8 * 128), 16, 0, 0);
      __builtin_amdgcn_global_load_lds((AS1 void*)(gb + (size_t)t * 8 * K + kt),
                                       (AS3 void*)(lb0 + t * 8 * 128), 16, 0, 0);
    }
    __syncthreads();
#pragma unroll
    for (int kk = 0; kk < 2; kk++){
      s16x8 af[4], bfr[4];
#pragma unroll
      for (int mf = 0; mf < 4; mf++)
        af[mf] = *(const s16x8*)&lA[(wm + mf * 16 + (l & 15)) * 64 + kk * 32 + (l >> 4) * 8];
#pragma unroll
      for (int nf = 0; nf < 4; nf++)
        bfr[nf] = *(const s16x8*)&lB[(wn + nf * 16 + (l & 15)) * 64 + kk * 32 + (l >> 4) * 8];
#pragma unroll
      for (int mf = 0; mf < 4; mf++)
#pragma unroll
        for (int nf = 0; nf < 4; nf++)
          acc[mf][nf] = __builtin_amdgcn_mfma_f32_16x16x32_bf16(
              __builtin_bit_cast(bf16x8, af[mf]),
              __builtin_bit_cast(bf16x8, bfr[nf]),
              acc[mf][nf], 0, 0, 0);
    }
  }
#pragma unroll
  for (int mf = 0; mf < 4; mf++){
#pragma unroll
    for (int r = 0; r < 4; r++){
      int row = tm + wm + mf * 16 + (l >> 4) * 4 + r;
      if (row < Mreal){
        float d = dis[row];
#pragma unroll
        for (int nf = 0; nf < 4; nf++){
          int col = tn + wn + nf * 16 + (l & 15);
          C[(size_t)row * N + col] = (uint16_t)f2bf1(acc[mf][nf][r] * d);
        }
      }
    }
  }
}

// ---------------- SpMM (CSR gather-sum), uint2 (4 bf16) per lane, 8-deep unroll ----------------
// MODE 0: STRC (no self/dis/bias; out bf16)  MODE 1: GCN (self+dis+bias; out bf16)
// MODE 2: GCN (self+dis+bias; out f32).  FHW = uint2 words per row = features/4.
template<int FHW, int MODE, int NPB>
__global__ void k_spmm(const uint2* __restrict__ X,
                       const int* __restrict__ off, const int* __restrict__ adj,
                       const float* __restrict__ dis, const float* __restrict__ bias,
                       void* __restrict__ outp){
  const int n = blockIdx.x * NPB + threadIdx.x / FHW;
  const int t = threadIdx.x % FHW;
  int s = off[n], e = off[n + 1];
  float a0 = 0.f, a1 = 0.f, a2 = 0.f, a3 = 0.f;
  if (MODE != 0){
    uint2 v = X[(size_t)n * FHW + t];   // self-loop term
    a0 = bflo(v.x); a1 = bfhi(v.x); a2 = bflo(v.y); a3 = bfhi(v.y);
  }
  int j = s;
  for (; j + 8 <= e; j += 8){
    int rr[8];
#pragma unroll
    for (int u = 0; u < 8; u++) rr[u] = adj[j + u];
#pragma unroll
    for (int u = 0; u < 8; u++){
      uint2 v = X[(size_t)rr[u] * FHW + t];
      a0 += bflo(v.x); a1 += bfhi(v.x); a2 += bflo(v.y); a3 += bfhi(v.y);
    }
  }
  for (; j < e; ++j){
    uint2 v = X[(size_t)adj[j] * FHW + t];
    a0 += bflo(v.x); a1 += bfhi(v.x); a2 += bflo(v.y); a3 += bfhi(v.y);
  }
  if (MODE != 0){
    float d = dis[n];
    float4 b = ((const float4*)bias)[t];
    a0 = fmaf(a0, d, b.x); a1 = fmaf(a1, d, b.y);
    a2 = fmaf(a2, d, b.z); a3 = fmaf(a3, d, b.w);
  }
  if (MODE == 2) ((float4*)outp)[(size_t)n * FHW + t] = make_float4(a0, a1, a2, a3);
  else           ((uint2*)outp)[(size_t)n * FHW + t] = make_uint2(f2bf2(a0, a1), f2bf2(a2, a3));
}

// ---------------- BN ----------------
template<int FH>
__global__ void k_stats(const uint32_t* __restrict__ X, float* __restrict__ sums){
  const int t = threadIdx.x;
  float sx = 0, sy = 0, qx = 0, qy = 0;
  for (int r = blockIdx.x; r < NND; r += gridDim.x){
    uint32_t v = X[(size_t)r * FH + t];
    float x = bflo(v), y = bfhi(v);
    sx += x; sy += y; qx += x * x; qy += y * y;
  }
  atomicAdd(&sums[2 * t    ], sx);
  atomicAdd(&sums[2 * t + 1], sy);
  atomicAdd(&sums[2 * FH + 2 * t    ], qx);
  atomicAdd(&sums[2 * FH + 2 * t + 1], qy);
}

__global__ void k_bnfin(const float* __restrict__ sums, int F, float inv,
                        const float* __restrict__ gamma, const float* __restrict__ beta,
                        float* __restrict__ scsh){
  int f = blockIdx.x * blockDim.x + threadIdx.x;
  if (f >= F) return;
  float mu  = sums[f] * inv;
  float var = fmaxf(sums[F + f] * inv - mu * mu, 0.f);
  float sc  = gamma[f] * rsqrtf(var + EPS_BN);
  scsh[f]     = sc;
  scsh[F + f] = beta[f] - mu * sc;
}

template<int FH, bool RELU>
__global__ void k_bnapply(const uint32_t* __restrict__ X, const float* __restrict__ scsh,
                          uint32_t* __restrict__ out){
  size_t i = (size_t)blockIdx.x * blockDim.x + threadIdx.x;
  if (i >= (size_t)NND * FH) return;
  int t = (int)(i & (FH - 1));
  uint32_t v = X[i];
  float2 sc = ((const float2*)scsh)[t];
  float2 sh = ((const float2*)(scsh + 2 * FH))[t];
  float x = fmaf(sc.x, bflo(v), sh.x);
  float y = fmaf(sc.y, bfhi(v), sh.y);
  if (RELU){ x = fmaxf(x, 0.f); y = fmaxf(y, 0.f); }
  out[i] = f2bf2(x, y);
}

// ---------------- final combine ----------------
__global__ void k_final(const float2* __restrict__ x2, const uint32_t* __restrict__ wc1,
                        const uint32_t* __restrict__ t2, const float* __restrict__ scsh,
                        const float* __restrict__ policy, float2* __restrict__ outp){
  size_t i = (size_t)blockIdx.x * blockDim.x + threadIdx.x;
  if (i >= (size_t)NND * 128) return;
  int t = (int)(i & 127);
  float2 sc = ((const float2*)scsh)[t];
  float2 sh = ((const float2*)(scsh + 256))[t];
  float a = policy[0], b = policy[1];
  float m = fmaxf(a, b);
  float e0 = expf(a - m), e1 = expf(b - m);
  float p0 = e0 / (e0 + e1), p1 = 1.f - p0;
  uint32_t w = wc1[i], v = t2[i];
  float xax = 0.5f * (bflo(w) + fmaf(sc.x, bflo(v), sh.x));
  float xay = 0.5f * (bfhi(w) + fmaf(sc.y, bfhi(v), sh.y));
  float2 xv = x2[i];
  outp[i] = make_float2(fmaf(p0, xv.x, p1 * xax), fmaf(p0, xv.y, p1 * xay));
}

// ---------------- launcher ----------------
extern "C" void kernel_launch(void* const* d_in, const int* in_sizes, int n_in,
                              void* d_out, int out_size, void* d_ws, size_t ws_size,
                              hipStream_t stream) {
  const float* node_feat = (const float*)d_in[0];
  const float* W1    = (const float*)d_in[1];
  const float* b1    = (const float*)d_in[2];
  const float* W2    = (const float*)d_in[3];
  const float* b2    = (const float*)d_in[4];
  const float* g1    = (const float*)d_in[5];
  const float* be1   = (const float*)d_in[6];
  const float* strcW = (const float*)d_in[7];
  const float* sg    = (const float*)d_in[8];
  const float* sb    = (const float*)d_in[9];
  const float* pol   = (const float*)d_in[10];
  const int*   eidx  = (const int*)d_in[11];
  const int E = in_sizes[11] / 2;
  const int* row0 = eidx;
  const int* col0 = eidx + E;

  char* w = (char*)d_ws;
  auto alloc = [&](size_t bytes) -> char* {
    char* p = w; w += (bytes + 255) & ~(size_t)255; return p;
  };
  char* meta0   = w;
  int*  cnt_col = (int*)alloc(50176 * 4);
  int*  cnt_row = (int*)alloc(50176 * 4);
  int*  off_col = (int*)alloc(50432 * 4);
  int*  off_row = (int*)alloc(50432 * 4);
  int*  cur_col = (int*)alloc(50176 * 4);
  int*  cur_row = (int*)alloc(50176 * 4);
  int*  bsum    = (int*)alloc(512 * 4);
  int*  boff    = (int*)alloc(512 * 4);
  float* dis    = (float*)alloc(50048 * 4);
  float* sums1  = (float*)alloc(1024 * 4);
  float* sums2  = (float*)alloc(512 * 4);
  float* sums3  = (float*)alloc(512 * 4);
  float* scsh1  = (float*)alloc(1024 * 4);
  float* scsh2  = (float*)alloc(512 * 4);
  float* scsh3  = (float*)alloc(512 * 4);
  char* meta1   = w;
  int*  adjA = (int*)alloc((size_t)E * 4);
  int*  adjB = (int*)alloc((size_t)E * 4);
  uint16_t* W1t = (uint16_t*)alloc(512 * 512 * 2);
  uint16_t* W2t = (uint16_t*)alloc(256 * 512 * 2);
  char* BUF_B = alloc((size_t)NPAD * 512 * 2);  // Xb -> agg1b -> H2b -> temp/temp2
  char* BUF_C = alloc((size_t)NPAD * 512 * 2);  // Hb -> X2b -> x2(f32)
  char* BUF_D = alloc((size_t)NND * 256 * 2);   // strcW bf16 -> Wc1 bf16
  (void)n_in; (void)out_size; (void)ws_size;

  hipMemsetAsync(meta0, 0, (size_t)(meta1 - meta0), stream);
  hipMemsetAsync(BUF_B + (size_t)NND * 1024, 0, (size_t)(NPAD - NND) * 1024, stream);

  const int EB = (E + 255) / 256;
  // CSR build
  k_count<<<EB, 256, 0, stream>>>(row0, col0, E, cnt_col, cnt_row);
  k_scan1<<<dim3(NBLK, 2), 256, 0, stream>>>(cnt_col, cnt_row, bsum);
  k_scan2<<<dim3(1, 2), 256, 0, stream>>>(bsum, boff);
  k_scan3<<<dim3(NBLK, 2), 256, 0, stream>>>(cnt_col, cnt_row, boff,
                                             off_col, off_row, cur_col, cur_row);
  k_dis<<<(NND + 255) / 256, 256, 0, stream>>>(cnt_col, dis);
  k_fill<<<NRANGE * EB, 256, 0, stream>>>(row0, col0, E, EB, cur_col, cur_row, adjA, adjB);

  // casts
  k_cast<<<(NND * 128 + 255) / 256, 256, 0, stream>>>(node_feat, (uint2*)BUF_B, (size_t)NND * 128);
  k_cast<<<(NND * 64 + 255) / 256, 256, 0, stream>>>(strcW, (uint2*)BUF_D, (size_t)NND * 64);
  k_castT<<<dim3(16, 16), 256, 0, stream>>>(W1, W1t, 512, 512);
  k_castT<<<dim3(16, 8), 256, 0, stream>>>(W2, W2t, 512, 256);

  // GCN conv1
  k_gemm<<<dim3(NPAD / 128, 4), 256, 0, stream>>>((const uint16_t*)BUF_B, W1t,
                                                  (uint16_t*)BUF_C, dis, 512, 512, NND);
  k_spmm<128, 1, 2><<<NND / 2, 256, 0, stream>>>((const uint2*)BUF_C, off_col, adjA,
                                                 dis, b1, BUF_B);            // agg1 bf16 -> B
  k_stats<256><<<512, 256, 0, stream>>>((const uint32_t*)BUF_B, sums1);
  k_bnfin<<<2, 256, 0, stream>>>(sums1, 512, 1.f / NND, g1, be1, scsh1);
  hipMemsetAsync(BUF_C + (size_t)NND * 1024, 0, (size_t)(NPAD - NND) * 1024, stream);
  k_bnapply<256, true><<<(NND * 256 + 255) / 256, 256, 0, stream>>>(
      (const uint32_t*)BUF_B, scsh1, (uint32_t*)BUF_C);
  // GCN conv2
  k_gemm<<<dim3(NPAD / 128, 2), 256, 0, stream>>>((const uint16_t*)BUF_C, W2t,
                                                  (uint16_t*)BUF_B, dis, 512, 256, NND);
  k_spmm<64, 2, 2><<<NND / 2, 128, 0, stream>>>((const uint2*)BUF_B, off_col, adjA,
                                                dis, b2, BUF_C);             // x2 f32 -> C

  // STRC branch
  k_spmm<64, 0, 2><<<NND / 2, 128, 0, stream>>>((const uint2*)BUF_D, off_row, adjB,
                                                nullptr, nullptr, BUF_B);    // temp bf16 -> B
  k_stats<128><<<512, 128, 0, stream>>>((const uint32_t*)BUF_B, sums2);
  k_bnfin<<<1, 256, 0, stream>>>(sums2, 256, 1.f / NND, sg, sb, scsh2);
  k_bnapply<128, false><<<(NND * 128 + 255) / 256, 256, 0, stream>>>(
      (const uint32_t*)BUF_B, scsh2, (uint32_t*)BUF_D);                      // Wc1 bf16 -> D
  k_spmm<64, 0, 2><<<NND / 2, 128, 0, stream>>>((const uint2*)BUF_D, off_row, adjB,
                                                nullptr, nullptr, BUF_B);    // temp2 bf16 -> B
  k_stats<128><<<512, 128, 0, stream>>>((const uint32_t*)BUF_B, sums3);
  k_bnfin<<<1, 256, 0, stream>>>(sums3, 256, 1.f / NND, sg + 256, sb + 256, scsh3);

  k_final<<<(NND * 128 + 255) / 256, 256, 0, stream>>>(
      (const float2*)BUF_C, (const uint32_t*)BUF_D, (const uint32_t*)BUF_B,
      scsh3, pol, (float2*)d_out);
}

// Round 3
// 1264.475 us; speedup vs baseline: 1.1703x; 1.0863x over previous
//
#include <hip/hip_runtime.h>
#include <stdint.h>

#define NND   50000      // real nodes
#define NPAD  50048      // padded to 391*128 for GEMM M-tiles
#define NBLK  196        // ceil(50001/256) scan blocks
#define NRANGE 7         // fill rounds: dst>>13, max 49999>>13 = 6
#define EPS_BN 1e-5f

typedef __attribute__((ext_vector_type(8))) short    s16x8;
typedef __attribute__((ext_vector_type(8))) __bf16   bf16x8;
typedef __attribute__((ext_vector_type(4))) float    f32x4;

#define AS1 __attribute__((address_space(1)))
#define AS3 __attribute__((address_space(3)))

__device__ __forceinline__ float bflo(uint32_t v){ return __uint_as_float(v << 16); }
__device__ __forceinline__ float bfhi(uint32_t v){ return __uint_as_float(v & 0xffff0000u); }
__device__ __forceinline__ uint32_t f2bf1(float f){
  uint32_t u = __float_as_uint(f);
  return (u + 0x7fffu + ((u >> 16) & 1u)) >> 16;   // RNE
}
__device__ __forceinline__ uint32_t f2bf2(float lo, float hi){
  return f2bf1(lo) | (f2bf1(hi) << 16);
}

// ---------------- CSR build ----------------
__global__ void k_count(const int* __restrict__ row0, const int* __restrict__ col0, int E,
                        int* __restrict__ cnt_col, int* __restrict__ cnt_row){
  int e = blockIdx.x * 256 + threadIdx.x;
  if (e < E){
    atomicAdd(&cnt_col[col0[e]], 1);
    atomicAdd(&cnt_row[row0[e]], 1);
  }
}

__global__ void k_scan1(const int* __restrict__ ca, const int* __restrict__ cb,
                        int* __restrict__ bsum){
  const int* c = blockIdx.y ? cb : ca;
  int i = blockIdx.x * 256 + threadIdx.x;
  int v = (i < NND) ? c[i] : 0;
  __shared__ int s[256];
  s[threadIdx.x] = v; __syncthreads();
  for (int o = 128; o > 0; o >>= 1){
    if (threadIdx.x < o) s[threadIdx.x] += s[threadIdx.x + o];
    __syncthreads();
  }
  if (threadIdx.x == 0) bsum[blockIdx.y * NBLK + blockIdx.x] = s[0];
}

__global__ void k_scan2(const int* __restrict__ bsum, int* __restrict__ boff){
  int a = blockIdx.y, t = threadIdx.x;
  int v = (t < NBLK) ? bsum[a * NBLK + t] : 0;
  __shared__ int s[256];
  s[t] = v; __syncthreads();
  for (int o = 1; o < 256; o <<= 1){
    int x = (t >= o) ? s[t - o] : 0; __syncthreads();
    s[t] += x; __syncthreads();
  }
  if (t < NBLK) boff[a * NBLK + t] = s[t] - v;   // exclusive
}

__global__ void k_scan3(const int* __restrict__ ca, const int* __restrict__ cb,
                        const int* __restrict__ boff,
                        int* __restrict__ offa, int* __restrict__ offb,
                        int* __restrict__ cura, int* __restrict__ curb){
  int a = blockIdx.y, t = threadIdx.x;
  const int* c = a ? cb : ca;
  int* off = a ? offb : offa;
  int* cur = a ? curb : cura;
  int i = blockIdx.x * 256 + t;
  int v = (i < NND) ? c[i] : 0;
  __shared__ int s[256];
  s[t] = v; __syncthreads();
  for (int o = 1; o < 256; o <<= 1){
    int x = (t >= o) ? s[t - o] : 0; __syncthreads();
    s[t] += x; __syncthreads();
  }
  int excl = s[t] - v + boff[a * NBLK + blockIdx.x];
  if (i <= NND){ off[i] = excl; if (i < NND) cur[i] = excl; }
}

__global__ void k_dis(const int* __restrict__ cnt_col, float* __restrict__ dis){
  int i = blockIdx.x * 256 + threadIdx.x;
  if (i < NND) dis[i] = rsqrtf((float)(cnt_col[i] + 1));   // deg incl self-loop >= 1
}

// Range-partitioned fill (round-1 win: keeps scatter region L2-resident)
__global__ void k_fill(const int* __restrict__ row0, const int* __restrict__ col0,
                       int E, int EB,
                       int* __restrict__ cur_col, int* __restrict__ cur_row,
                       int* __restrict__ adjA, int* __restrict__ adjB){
  int round = blockIdx.x / EB;
  int e = (blockIdx.x - round * EB) * 256 + threadIdx.x;
  if (e >= E) return;
  int r = row0[e], c = col0[e];
  if ((c >> 13) == round) adjA[atomicAdd(&cur_col[c], 1)] = r;
  if ((r >> 13) == round) adjB[atomicAdd(&cur_row[r], 1)] = c;
}

// ---------------- casts ----------------
__global__ void k_cast(const float* __restrict__ x, uint2* __restrict__ o, size_t nq){
  size_t i = (size_t)blockIdx.x * blockDim.x + threadIdx.x;
  if (i < nq){
    float4 v = ((const float4*)x)[i];
    o[i] = make_uint2(f2bf2(v.x, v.y), f2bf2(v.z, v.w));
  }
}

// W [K][N] f32 -> Wt [N][K] bf16
__global__ void k_castT(const float* __restrict__ W, uint16_t* __restrict__ Wt, int K, int N){
  __shared__ float tile[32][33];
  int k0 = blockIdx.x * 32, n0 = blockIdx.y * 32;
  int tx = threadIdx.x & 31, ty = threadIdx.x >> 5;
  for (int j = ty; j < 32; j += 8) tile[j][tx] = W[(size_t)(k0 + j) * N + n0 + tx];
  __syncthreads();
  for (int j = ty; j < 32; j += 8)
    Wt[(size_t)(n0 + j) * K + k0 + tx] = (uint16_t)f2bf1(tile[tx][j]);
}

// ---------------- bf16 MFMA GEMM ----------------
__global__ __launch_bounds__(256) void k_gemm(
    const uint16_t* __restrict__ A, const uint16_t* __restrict__ Bt,
    uint16_t* __restrict__ C, const float* __restrict__ dis,
    int K, int N, int Mreal){
  __shared__ uint16_t lA[128 * 64];
  __shared__ uint16_t lB[128 * 64];
  const int tid = threadIdx.x, w = tid >> 6, l = tid & 63;
  const int tm = blockIdx.x * 128, tn = blockIdx.y * 128;
  const int wm = (w >> 1) * 64, wn = (w & 1) * 64;
  f32x4 acc[4][4] = {};
  const int srow = w * 32 + (l >> 3);
  const int kcol = (l & 7) * 8;
  const uint16_t* ga = A  + (size_t)(tm + srow) * K + kcol;
  const uint16_t* gb = Bt + (size_t)(tn + srow) * K + kcol;
  char* la0 = (char*)lA + (w * 32) * 128;
  char* lb0 = (char*)lB + (w * 32) * 128;

  for (int kt = 0; kt < K; kt += 64){
    __syncthreads();
#pragma unroll
    for (int t = 0; t < 4; t++){
      __builtin_amdgcn_global_load_lds((AS1 void*)(ga + (size_t)t * 8 * K + kt),
                                       (AS3 void*)(la0 + t * 8 * 128), 16, 0, 0);
      __builtin_amdgcn_global_load_lds((AS1 void*)(gb + (size_t)t * 8 * K + kt),
                                       (AS3 void*)(lb0 + t * 8 * 128), 16, 0, 0);
    }
    __syncthreads();
#pragma unroll
    for (int kk = 0; kk < 2; kk++){
      s16x8 af[4], bfr[4];
#pragma unroll
      for (int mf = 0; mf < 4; mf++)
        af[mf] = *(const s16x8*)&lA[(wm + mf * 16 + (l & 15)) * 64 + kk * 32 + (l >> 4) * 8];
#pragma unroll
      for (int nf = 0; nf < 4; nf++)
        bfr[nf] = *(const s16x8*)&lB[(wn + nf * 16 + (l & 15)) * 64 + kk * 32 + (l >> 4) * 8];
#pragma unroll
      for (int mf = 0; mf < 4; mf++)
#pragma unroll
        for (int nf = 0; nf < 4; nf++)
          acc[mf][nf] = __builtin_amdgcn_mfma_f32_16x16x32_bf16(
              __builtin_bit_cast(bf16x8, af[mf]),
              __builtin_bit_cast(bf16x8, bfr[nf]),
              acc[mf][nf], 0, 0, 0);
    }
  }
#pragma unroll
  for (int mf = 0; mf < 4; mf++){
#pragma unroll
    for (int r = 0; r < 4; r++){
      int row = tm + wm + mf * 16 + (l >> 4) * 4 + r;
      if (row < Mreal){
        float d = dis[row];
#pragma unroll
        for (int nf = 0; nf < 4; nf++){
          int col = tn + wn + nf * 16 + (l & 15);
          C[(size_t)row * N + col] = (uint16_t)f2bf1(acc[mf][nf][r] * d);
        }
      }
    }
  }
}

// ---------------- feature-chunked SpMM ----------------
// 16 nodes/block, 16 uint2-words (64 feats) per node per pass; gridDim.y = pass.
// Blocks dispatch x-major -> co-resident blocks share a chunk -> small gather
// working set stays L2-resident.
// MODE 0: STRC (no self/dis/bias; out bf16)
// MODE 1: GCN  (self+dis+bias; out bf16)
// MODE 3: GCN  (self+dis+bias) fused with final combine; out f32
template<int FHW, int MODE>
__global__ __launch_bounds__(256) void k_spmm(const uint2* __restrict__ X,
                       const int* __restrict__ off, const int* __restrict__ adj,
                       const float* __restrict__ dis, const float* __restrict__ bias,
                       void* __restrict__ outp,
                       const uint2* __restrict__ wc1, const uint2* __restrict__ t2,
                       const float* __restrict__ scsh, const float* __restrict__ policy){
  const int ln  = threadIdx.x >> 4;
  const int wrd = threadIdx.x & 15;
  const int n   = blockIdx.x * 16 + ln;
  const int wb  = blockIdx.y * 16 + wrd;
  const size_t rowi = (size_t)n * FHW + wb;
  int s = off[n], e = off[n + 1];
  float a0 = 0.f, a1 = 0.f, a2 = 0.f, a3 = 0.f;
  if (MODE != 0){
    uint2 v = X[rowi];   // self-loop term
    a0 = bflo(v.x); a1 = bfhi(v.x); a2 = bflo(v.y); a3 = bfhi(v.y);
  }
  int j = s;
  for (; j + 8 <= e; j += 8){
    int rr[8];
#pragma unroll
    for (int u = 0; u < 8; u++) rr[u] = adj[j + u];
#pragma unroll
    for (int u = 0; u < 8; u++){
      uint2 v = X[(size_t)rr[u] * FHW + wb];
      a0 += bflo(v.x); a1 += bfhi(v.x); a2 += bflo(v.y); a3 += bfhi(v.y);
    }
  }
  for (; j < e; ++j){
    uint2 v = X[(size_t)adj[j] * FHW + wb];
    a0 += bflo(v.x); a1 += bfhi(v.x); a2 += bflo(v.y); a3 += bfhi(v.y);
  }
  if (MODE == 0){
    ((uint2*)outp)[rowi] = make_uint2(f2bf2(a0, a1), f2bf2(a2, a3));
  } else {
    float d = dis[n];
    float4 b4 = ((const float4*)bias)[wb];
    a0 = fmaf(a0, d, b4.x); a1 = fmaf(a1, d, b4.y);
    a2 = fmaf(a2, d, b4.z); a3 = fmaf(a3, d, b4.w);
    if (MODE == 1){
      ((uint2*)outp)[rowi] = make_uint2(f2bf2(a0, a1), f2bf2(a2, a3));
    } else {
      // fused final: out = p0*x2 + p1*0.5*(Wc1 + bn3(t2))
      float pa = policy[0], pb = policy[1];
      float mx = fmaxf(pa, pb);
      float e0 = expf(pa - mx), e1 = expf(pb - mx);
      float p0 = e0 / (e0 + e1), p1 = 1.f - p0;
      uint2 wv = wc1[rowi];
      uint2 tv = t2[rowi];
      float4 sc = ((const float4*)scsh)[wb];
      float4 sh = ((const float4*)(scsh + 256))[wb];
      float x0 = 0.5f * (bflo(wv.x) + fmaf(sc.x, bflo(tv.x), sh.x));
      float x1 = 0.5f * (bfhi(wv.x) + fmaf(sc.y, bfhi(tv.x), sh.y));
      float x2 = 0.5f * (bflo(wv.y) + fmaf(sc.z, bflo(tv.y), sh.z));
      float x3 = 0.5f * (bfhi(wv.y) + fmaf(sc.w, bfhi(tv.y), sh.w));
      float4 o;
      o.x = fmaf(p0, a0, p1 * x0); o.y = fmaf(p0, a1, p1 * x1);
      o.z = fmaf(p0, a2, p1 * x2); o.w = fmaf(p0, a3, p1 * x3);
      ((float4*)outp)[rowi] = o;
    }
  }
}

// ---------------- BN ----------------
template<int FH>
__global__ void k_stats(const uint32_t* __restrict__ X, float* __restrict__ sums){
  const int t = threadIdx.x;
  float sx = 0, sy = 0, qx = 0, qy = 0;
  for (int r = blockIdx.x; r < NND; r += gridDim.x){
    uint32_t v = X[(size_t)r * FH + t];
    float x = bflo(v), y = bfhi(v);
    sx += x; sy += y; qx += x * x; qy += y * y;
  }
  atomicAdd(&sums[2 * t    ], sx);
  atomicAdd(&sums[2 * t + 1], sy);
  atomicAdd(&sums[2 * FH + 2 * t    ], qx);
  atomicAdd(&sums[2 * FH + 2 * t + 1], qy);
}

__global__ void k_bnfin(const float* __restrict__ sums, int F, float inv,
                        const float* __restrict__ gamma, const float* __restrict__ beta,
                        float* __restrict__ scsh){
  int f = blockIdx.x * blockDim.x + threadIdx.x;
  if (f >= F) return;
  float mu  = sums[f] * inv;
  float var = fmaxf(sums[F + f] * inv - mu * mu, 0.f);
  float sc  = gamma[f] * rsqrtf(var + EPS_BN);
  scsh[f]     = sc;
  scsh[F + f] = beta[f] - mu * sc;
}

template<int FH, bool RELU>
__global__ void k_bnapply(const uint32_t* __restrict__ X, const float* __restrict__ scsh,
                          uint32_t* __restrict__ out){
  size_t i = (size_t)blockIdx.x * blockDim.x + threadIdx.x;
  if (i >= (size_t)NND * FH) return;
  int t = (int)(i & (FH - 1));
  uint32_t v = X[i];
  float2 sc = ((const float2*)scsh)[t];
  float2 sh = ((const float2*)(scsh + 2 * FH))[t];
  float x = fmaf(sc.x, bflo(v), sh.x);
  float y = fmaf(sc.y, bfhi(v), sh.y);
  if (RELU){ x = fmaxf(x, 0.f); y = fmaxf(y, 0.f); }
  out[i] = f2bf2(x, y);
}

// ---------------- launcher ----------------
extern "C" void kernel_launch(void* const* d_in, const int* in_sizes, int n_in,
                              void* d_out, int out_size, void* d_ws, size_t ws_size,
                              hipStream_t stream) {
  const float* node_feat = (const float*)d_in[0];
  const float* W1    = (const float*)d_in[1];
  const float* b1    = (const float*)d_in[2];
  const float* W2    = (const float*)d_in[3];
  const float* b2    = (const float*)d_in[4];
  const float* g1    = (const float*)d_in[5];
  const float* be1   = (const float*)d_in[6];
  const float* strcW = (const float*)d_in[7];
  const float* sg    = (const float*)d_in[8];
  const float* sb    = (const float*)d_in[9];
  const float* pol   = (const float*)d_in[10];
  const int*   eidx  = (const int*)d_in[11];
  const int E = in_sizes[11] / 2;
  const int* row0 = eidx;
  const int* col0 = eidx + E;

  char* w = (char*)d_ws;
  auto alloc = [&](size_t bytes) -> char* {
    char* p = w; w += (bytes + 255) & ~(size_t)255; return p;
  };
  char* meta0   = w;
  int*  cnt_col = (int*)alloc(50176 * 4);
  int*  cnt_row = (int*)alloc(50176 * 4);
  int*  off_col = (int*)alloc(50432 * 4);
  int*  off_row = (int*)alloc(50432 * 4);
  int*  cur_col = (int*)alloc(50176 * 4);
  int*  cur_row = (int*)alloc(50176 * 4);
  int*  bsum    = (int*)alloc(512 * 4);
  int*  boff    = (int*)alloc(512 * 4);
  float* dis    = (float*)alloc(50048 * 4);
  float* sums1  = (float*)alloc(1024 * 4);
  float* sums2  = (float*)alloc(512 * 4);
  float* sums3  = (float*)alloc(512 * 4);
  float* scsh1  = (float*)alloc(1024 * 4);
  float* scsh2  = (float*)alloc(512 * 4);
  float* scsh3  = (float*)alloc(512 * 4);
  char* meta1   = w;
  int*  adjA = (int*)alloc((size_t)E * 4);
  int*  adjB = (int*)alloc((size_t)E * 4);
  uint16_t* W1t = (uint16_t*)alloc(512 * 512 * 2);
  uint16_t* W2t = (uint16_t*)alloc(256 * 512 * 2);
  char* BUF_B = alloc((size_t)NPAD * 512 * 2);  // temp -> Xb -> agg1b -> H2b
  char* BUF_C = alloc((size_t)NPAD * 512 * 2);  // Hb -> X2b
  char* BUF_D = alloc((size_t)NND * 256 * 2);   // strcW bf16 -> Wc1 bf16
  char* BUF_E = alloc((size_t)NND * 256 * 2);   // temp2 (t2)
  (void)n_in; (void)out_size; (void)ws_size;

  hipMemsetAsync(meta0, 0, (size_t)(meta1 - meta0), stream);

  const int EB = (E + 255) / 256;
  // CSR build
  k_count<<<EB, 256, 0, stream>>>(row0, col0, E, cnt_col, cnt_row);
  k_scan1<<<dim3(NBLK, 2), 256, 0, stream>>>(cnt_col, cnt_row, bsum);
  k_scan2<<<dim3(1, 2), 256, 0, stream>>>(bsum, boff);
  k_scan3<<<dim3(NBLK, 2), 256, 0, stream>>>(cnt_col, cnt_row, boff,
                                             off_col, off_row, cur_col, cur_row);
  k_dis<<<(NND + 255) / 256, 256, 0, stream>>>(cnt_col, dis);
  k_fill<<<NRANGE * EB, 256, 0, stream>>>(row0, col0, E, EB, cur_col, cur_row, adjA, adjB);

  // ---- STRC branch first (so final combine can fuse into agg2) ----
  k_cast<<<(NND * 64 + 255) / 256, 256, 0, stream>>>(strcW, (uint2*)BUF_D, (size_t)NND * 64);
  k_spmm<64, 0><<<dim3(3125, 4), 256, 0, stream>>>((const uint2*)BUF_D, off_row, adjB,
      nullptr, nullptr, BUF_B, nullptr, nullptr, nullptr, nullptr);          // temp -> B
  k_stats<128><<<512, 128, 0, stream>>>((const uint32_t*)BUF_B, sums2);
  k_bnfin<<<1, 256, 0, stream>>>(sums2, 256, 1.f / NND, sg, sb, scsh2);
  k_bnapply<128, false><<<(NND * 128 + 255) / 256, 256, 0, stream>>>(
      (const uint32_t*)BUF_B, scsh2, (uint32_t*)BUF_D);                      // Wc1 -> D
  k_spmm<64, 0><<<dim3(3125, 4), 256, 0, stream>>>((const uint2*)BUF_D, off_row, adjB,
      nullptr, nullptr, BUF_E, nullptr, nullptr, nullptr, nullptr);          // temp2 -> E
  k_stats<128><<<512, 128, 0, stream>>>((const uint32_t*)BUF_E, sums3);
  k_bnfin<<<1, 256, 0, stream>>>(sums3, 256, 1.f / NND, sg + 256, sb + 256, scsh3);

  // ---- GCN branch ----
  k_cast<<<(NND * 128 + 255) / 256, 256, 0, stream>>>(node_feat, (uint2*)BUF_B, (size_t)NND * 128);
  hipMemsetAsync(BUF_B + (size_t)NND * 1024, 0, (size_t)(NPAD - NND) * 1024, stream);
  k_castT<<<dim3(16, 16), 256, 0, stream>>>(W1, W1t, 512, 512);
  k_castT<<<dim3(16, 8), 256, 0, stream>>>(W2, W2t, 512, 256);

  k_gemm<<<dim3(NPAD / 128, 4), 256, 0, stream>>>((const uint16_t*)BUF_B, W1t,
                                                  (uint16_t*)BUF_C, dis, 512, 512, NND);
  k_spmm<128, 1><<<dim3(3125, 8), 256, 0, stream>>>((const uint2*)BUF_C, off_col, adjA,
      dis, b1, BUF_B, nullptr, nullptr, nullptr, nullptr);                   // agg1 -> B
  k_stats<256><<<512, 256, 0, stream>>>((const uint32_t*)BUF_B, sums1);
  k_bnfin<<<2, 256, 0, stream>>>(sums1, 512, 1.f / NND, g1, be1, scsh1);
  hipMemsetAsync(BUF_C + (size_t)NND * 1024, 0, (size_t)(NPAD - NND) * 1024, stream);
  k_bnapply<256, true><<<(NND * 256 + 255) / 256, 256, 0, stream>>>(
      (const uint32_t*)BUF_B, scsh1, (uint32_t*)BUF_C);                      // X2b -> C
  k_gemm<<<dim3(NPAD / 128, 2), 256, 0, stream>>>((const uint16_t*)BUF_C, W2t,
                                                  (uint16_t*)BUF_B, dis, 512, 256, NND);
  // agg2 + fused final combine -> d_out (f32)
  k_spmm<64, 3><<<dim3(3125, 4), 256, 0, stream>>>((const uint2*)BUF_B, off_col, adjA,
      dis, b2, d_out, (const uint2*)BUF_D, (const uint2*)BUF_E, scsh3, pol);
}